// Round 5
// baseline (6623.026 us; speedup 1.0000x reference)
//
#include <hip/hip_runtime.h>

// LSTM T=16384, B=32, H=96. History: R15 dot2 = 6240us; R17 MFMA-rows = 7108
// (tail x4); R18 MFMA-cols = 5142us (verified layout; step ~377cy @~1.2GHz:
// ~145cy matrix (critical-SIMD 24 MFMA), ~109cy VALU, ~150cy DEAD = ds_read
// latency + write->barrier roundtrip, all waves lockstep-idle).
// R19 (this): fill the dead time with a SECOND batch in an INDEPENDENT SYNC
// DOMAIN. R16 failed because __syncthreads phase-locks both batches (stalls
// align: max not sum). Here: 16 blocks x 768 thr = 2 domains x 6 waves, each
// domain has its own LDS arena (NS=256 -> 54.9KB each) and its own LDS-flag
// barrier: lane0-per-wave atomic_add(release) + all-lane acquire spin until
// ctr >= 6*epoch. No s_barrier after init -> domains drift; one domain's
// read-latency/sync window is filled by the other's MFMA/VALU issue (every
// SIMD hosts waves of both domains). step() body = R18 verbatim: A = h
// replicated rows (3x ds_read_b128), B = weights cols (tile t col c -> cell
// 4t+(c>>2), gate c&3), acc reg0 + 3-cndmask tile select by h16, quad DPP
// tail, e_k prefold, scaled-domain c, gx off-chain.

constexpr int HH   = 96;
constexpr int BB   = 32;     // total batch
constexpr int TT   = 16384;
constexpr int THH  = 384;    // threads per domain (6 waves)
constexpr int TH   = 768;    // 12 waves, ~3/SIMD mixing both domains
constexpr int NB   = 16;     // blocks; 2 batches per block
constexpr int NS   = 256;    // h history window per domain
constexpr int ROWP = 104;    // halves per hist row: 208 B, 16B-aligned

typedef _Float16 f16x8 __attribute__((ext_vector_type(8)));
typedef _Float16 f16x2 __attribute__((ext_vector_type(2)));
typedef float    f32x4 __attribute__((ext_vector_type(4)));

template <int CTRL>
__device__ __forceinline__ float dpp_bcast(float v) {
    int r = __builtin_amdgcn_mov_dpp(__builtin_bit_cast(int, v), CTRL, 0xF, 0xF, true);
    return __builtin_bit_cast(float, r);
}
constexpr int DPP_B1 = 0x55;
constexpr int DPP_B2 = 0xAA;
constexpr int DPP_B3 = 0xFF;

#define LOG2E 1.44269504f

__attribute__((amdgpu_flat_work_group_size(TH, TH)))
__global__ void lstm_kernel(const float* __restrict__ x,
                            const float* __restrict__ w_ih,
                            const float* __restrict__ w_hh,
                            const float* __restrict__ b_ih,
                            const float* __restrict__ b_hh,
                            const float* __restrict__ fc_w,
                            const float* __restrict__ fc_b,
                            float* __restrict__ out) {
    __shared__ __align__(16) _Float16 hist[2][(NS + 1) * ROWP];  // 2x 53.5 KB
    __shared__ __align__(16) float xs[2][NS];                    // 2x 1 KB
    __shared__ float fcw_s[2][HH];
    __shared__ int ctr[2][32];   // one flag dword per domain, bank-padded

    const int tid  = threadIdx.x;
    const int dom  = (tid >= THH) ? 1 : 0;
    const int stid = tid - dom * THH;
    const int b    = blockIdx.x * 2 + dom;   // global batch index
    const int wv   = stid >> 6;   // wave-in-domain 0..5, owns cells [16wv,+16)
    const int l    = stid & 63;
    const int h16  = l >> 4;      // k-group; also this lane's TILE index
    const int rIn  = l & 15;      // col within tile
    const int s    = rIn & 3;     // gate 0..3 (quad lane)
    const int q    = rIn >> 2;    // cell-sub within tile
    const int j    = 16 * wv + 4 * h16 + q;  // this lane's cell 0..95

    if (tid < 2) ctr[tid][0] = 0;
    __syncthreads();              // ONLY block-wide barrier (flag init)

    _Float16* __restrict__ histh = hist[dom];
    float*    __restrict__ xsh   = xs[dom];
    float*    __restrict__ fcwd  = fcw_s[dom];
    int* myctr = &ctr[dom][0];

    int epoch = 0;
    auto dsync = [&]() {          // per-domain 6-wave barrier via LDS flag
        ++epoch;
        if ((stid & 63) == 0)
            __hip_atomic_fetch_add(myctr, 1, __ATOMIC_RELEASE,
                                   __HIP_MEMORY_SCOPE_WORKGROUP);
        while (__hip_atomic_load(myctr, __ATOMIC_ACQUIRE,
                                 __HIP_MEMORY_SCOPE_WORKGROUP) < 6 * epoch) {}
    };

    // B fragments (weights), e_k-prescaled. Tile t col rIn holds W row
    // (gate s, cell 16wv+4t+q); lane's k slice = kt*32 + 8*h16 + e.
    const float ek_s = (s == 2) ? (-2.0f * LOG2E) : (-LOG2E);
    f16x8 Bw[4][3];
#pragma unroll
    for (int t = 0; t < 4; ++t) {
        const float* wrow = w_hh + (s * HH + 16 * wv + 4 * t + q) * HH;
#pragma unroll
        for (int kt = 0; kt < 3; ++kt) {
            const float* wr = wrow + kt * 32 + 8 * h16;
            f16x8 v;
#pragma unroll
            for (int e = 0; e < 8; ++e) v[e] = (_Float16)(wr[e] * ek_s);
            Bw[t][kt] = v;
        }
    }
#pragma unroll
    for (int t = 0; t < 4; ++t)
#pragma unroll
        for (int kt = 0; kt < 3; ++kt) asm volatile("" : "+v"(Bw[t][kt]));

    const float wih2  = w_ih[s * HH + j] * ek_s;
    const float bias2 = (b_ih[s * HH + j] + b_hh[s * HH + j]) * ek_s;
    const float a_mul = (s == 2) ? (-4.0f * LOG2E) : 1.0f;
    const float a_add = (s == 2) ? (2.0f * LOG2E) : 0.0f;
    const bool  t1 = (h16 == 1), t2 = (h16 == 2), t3 = (h16 == 3);

    const float fcb = fc_b[0];
    float c = 0.0f;   // scaled domain: c' = -2*log2e * c_true

    for (int i = stid; i < HH; i += THH) fcwd[i] = fc_w[i];

    // Bulk fc projection for window [t0, t0+NS): h(t0+i) is in hist row i+1.
    auto flush = [&](int t0) {
        for (int i = stid; i < NS; i += THH) {
            const uint2* hr = (const uint2*)(histh + (i + 1) * ROWP);
            float a = 0.0f;
#pragma unroll
            for (int m = 0; m < 24; ++m) {
                uint2 u = hr[m];
                f16x2 p0 = __builtin_bit_cast(f16x2, u.x);
                f16x2 p1 = __builtin_bit_cast(f16x2, u.y);
                a = fmaf((float)p0.x, fcwd[4 * m + 0], a);
                a = fmaf((float)p0.y, fcwd[4 * m + 1], a);
                a = fmaf((float)p1.x, fcwd[4 * m + 2], a);
                a = fmaf((float)p1.y, fcwd[4 * m + 3], a);
            }
            out[(t0 + i) * BB + b] = a + fcb + xsh[i];
        }
    };

    const _Float16* rd_p;  // h(t-1) k-slice base (8*h16); +4 rows per block
    _Float16*       wr_p;  // h(t) cell slot base

    auto step = [&](float gx, const int ofs) {   // ofs: constant element offset
        const uint4* p = (const uint4*)(rd_p + ofs);
        uint4 u0 = p[0], u1 = p[4], u2 = p[8];   // kt stride: 32 halves = 64B
        const f16x8 a0 = __builtin_bit_cast(f16x8, u0);
        const f16x8 a1 = __builtin_bit_cast(f16x8, u1);
        const f16x8 a2 = __builtin_bit_cast(f16x8, u2);

        f32x4 acc[4] = {{0.f, 0.f, 0.f, 0.f}, {0.f, 0.f, 0.f, 0.f},
                        {0.f, 0.f, 0.f, 0.f}, {0.f, 0.f, 0.f, 0.f}};
        // kt-outer: 4 independent tile-chains interleave, hiding MFMA latency.
#pragma unroll
        for (int t = 0; t < 4; ++t)
            acc[t] = __builtin_amdgcn_mfma_f32_16x16x32_f16(a0, Bw[t][0], acc[t], 0, 0, 0);
#pragma unroll
        for (int t = 0; t < 4; ++t)
            acc[t] = __builtin_amdgcn_mfma_f32_16x16x32_f16(a1, Bw[t][1], acc[t], 0, 0, 0);
#pragma unroll
        for (int t = 0; t < 4; ++t)
            acc[t] = __builtin_amdgcn_mfma_f32_16x16x32_f16(a2, Bw[t][2], acc[t], 0, 0, 0);

        // Rows are replicas -> reg 0 always; 3-cndmask tile select by h16.
        float v = t1 ? acc[1][0] : acc[0][0];
        v       = t2 ? acc[2][0] : v;
        v       = t3 ? acc[3][0] : v;

        const float pre = v + gx;
        const float act =
            fmaf(__builtin_amdgcn_rcpf(1.0f + __builtin_amdgcn_exp2f(pre)),
                 a_mul, a_add);
        const float fv = dpp_bcast<DPP_B1>(act);
        const float gv = dpp_bcast<DPP_B2>(act);   // already -2k-scaled
        const float ov = dpp_bcast<DPP_B3>(act);
        c = fmaf(fv, c, act * gv);                 // scaled domain
        const float rt = __builtin_amdgcn_rcpf(1.0f + __builtin_amdgcn_exp2f(c));
        const float h  = fmaf(ov + ov, rt, -ov);   // o * tanh(c_true)
        if (s == 0) *(wr_p + ofs) = (_Float16)h;
        dsync();
    };

    for (int w = 0; w < TT / NS; ++w) {
        const int t0 = w * NS;
        if (w == 0) {
            if (stid < 48) ((uint32_t*)histh)[stid] = 0u;  // row 0 = h(-1) = 0
        } else {
            flush(t0 - NS);                                // old xs + rows 1..NS
            if (stid < 48)                                 // row NS -> row 0
                ((uint32_t*)histh)[stid] =
                    ((const uint32_t*)(histh + NS * ROWP))[stid];
        }
        dsync();
        for (int i = stid; i < NS; i += THH) xsh[i] = x[(t0 + i) * BB + b];
        dsync();

        rd_p = histh + 8 * h16;
        wr_p = histh + ROWP + j;
        for (int tt = 0; tt < NS; tt += 4) {
            const float4 xq = *(const float4*)(xsh + tt);  // broadcast
            const float gx0 = fmaf(xq.x, wih2, bias2);     // off-chain
            const float gx1 = fmaf(xq.y, wih2, bias2);
            const float gx2 = fmaf(xq.z, wih2, bias2);
            const float gx3 = fmaf(xq.w, wih2, bias2);
            step(gx0, 0 * ROWP);
            step(gx1, 1 * ROWP);
            step(gx2, 2 * ROWP);
            step(gx3, 3 * ROWP);
            rd_p += 4 * ROWP;
            wr_p += 4 * ROWP;
        }
    }
    flush(TT - NS);   // last window (loop ended with a dsync)
}

extern "C" void kernel_launch(void* const* d_in, const int* in_sizes, int n_in,
                              void* d_out, int out_size, void* d_ws, size_t ws_size,
                              hipStream_t stream) {
    const float* x    = (const float*)d_in[0];
    const float* w_ih = (const float*)d_in[1];
    const float* w_hh = (const float*)d_in[2];
    const float* b_ih = (const float*)d_in[3];
    const float* b_hh = (const float*)d_in[4];
    const float* fc_w = (const float*)d_in[5];
    const float* fc_b = (const float*)d_in[6];
    float* out = (float*)d_out;

    lstm_kernel<<<dim3(NB), dim3(TH), 0, stream>>>(x, w_ih, w_hh, b_ih, b_hh,
                                                   fc_w, fc_b, out);
}

// Round 7
// 4585.970 us; speedup vs baseline: 1.4442x; 1.4442x over previous
//
#include <hip/hip_runtime.h>

// LSTM T=16384, B=32, H=96. History: R18 (6 waves, MFMA-cols) = 5142us;
// R19 (spin-barrier dual domain) = 6623us FAILED (poll burns issue slots).
// Model pinned at 2.4GHz from R18: step 754cy = 466cy MFMA burst on the
// CRITICAL SIMD (6 waves -> {2,2,1,1}/SIMD -> 24 of the 72 MFMA/CU at
// ~19.4cy/MFMA/SIMD) + ~120cy post-barrier ds_read + ~90cy tail + ~50cy
// barrier. The burst is 33% longer than necessary from imbalance alone.
// R20 (resubmit; round 6 was an infra failure, no signal): 8 WAVES (512 thr),
// 12 cells/wave = 3 tiles x 3 kt = 9 MFMA per wave -> exactly 2 waves/SIMD ->
// critical burst 24->18 MFMA (466->350cy).
//   - gx folded into MFMA C-init ({gx,0,0,0}): lane (h16,rIn) seeds C elem
//     (row 4*h16, col rIn) of every tile and reads back exactly that elem of
//     its own tile -> post-burst add removed.
//   - lanes 48-63 (h16=3) still supply the k=24..31 A/B slices (all 4
//     k-groups feed each MFMA); their TAIL mirrors tile 2 (te=min(h16,2)),
//     h-write masked to h16<3. Only tail work is redundant, not MFMA.
//   - tile select now 2 cndmask (3 tiles).
// Unchanged from R18: A = h(t-1) replicated rows (3x ds_read_b128), B =
// weights cols (tile t col c -> cell 4t+(c>>2), gate c&3 -- HW-verified),
// quad DPP tail, e_k prefold, scaled-domain c, 513-row slot-shifted history,
// one s_barrier per step, bulk fc flush per 512-step window.

constexpr int HH   = 96;
constexpr int BB   = 32;
constexpr int TT   = 16384;
constexpr int TH   = 512;   // 8 waves, 2 per SIMD
constexpr int NS   = 512;   // h history window
constexpr int ROWP = 104;   // halves per hist row: 208 B, 16B-aligned

typedef _Float16 f16x8 __attribute__((ext_vector_type(8)));
typedef _Float16 f16x2 __attribute__((ext_vector_type(2)));
typedef float    f32x4 __attribute__((ext_vector_type(4)));

template <int CTRL>
__device__ __forceinline__ float dpp_bcast(float v) {
    int r = __builtin_amdgcn_mov_dpp(__builtin_bit_cast(int, v), CTRL, 0xF, 0xF, true);
    return __builtin_bit_cast(float, r);
}
constexpr int DPP_B1 = 0x55;
constexpr int DPP_B2 = 0xAA;
constexpr int DPP_B3 = 0xFF;

#define LOG2E 1.44269504f

__attribute__((amdgpu_flat_work_group_size(TH, TH)))
__global__ void lstm_kernel(const float* __restrict__ x,
                            const float* __restrict__ w_ih,
                            const float* __restrict__ w_hh,
                            const float* __restrict__ b_ih,
                            const float* __restrict__ b_hh,
                            const float* __restrict__ fc_w,
                            const float* __restrict__ fc_b,
                            float* __restrict__ out) {
    __shared__ __align__(16) _Float16 hist[(NS + 1) * ROWP];  // ~104 KB
    __shared__ __align__(16) float xs[NS];                    // 2 KB x window
    __shared__ float fcw_s[HH];

    const int tid = threadIdx.x;
    const int b   = blockIdx.x;
    const int wv  = tid >> 6;   // wave 0..7, owns cells [12wv, 12wv+12)
    const int l   = tid & 63;
    const int h16 = l >> 4;     // k-group 0..3; tail tile = min(h16,2)
    const int rIn = l & 15;     // col within tile
    const int s   = rIn & 3;    // gate 0..3 (quad lane)
    const int q   = rIn >> 2;   // cell-sub within tile
    const int te  = (h16 == 3) ? 2 : h16;    // tail tile (h16=3 mirrors 2)
    const int j   = 12 * wv + 4 * te + q;    // this lane's cell 0..95

    // B fragments (weights), e_k-prescaled. Tile t col rIn holds W row
    // (gate s, cell 12wv+4t+q); lane's k slice = kt*32 + 8*h16 + e.
    const float ek_s = (s == 2) ? (-2.0f * LOG2E) : (-LOG2E);
    f16x8 Bw[3][3];
#pragma unroll
    for (int t = 0; t < 3; ++t) {
        const float* wrow = w_hh + (s * HH + 12 * wv + 4 * t + q) * HH;
#pragma unroll
        for (int kt = 0; kt < 3; ++kt) {
            const float* wr = wrow + kt * 32 + 8 * h16;
            f16x8 v;
#pragma unroll
            for (int e = 0; e < 8; ++e) v[e] = (_Float16)(wr[e] * ek_s);
            Bw[t][kt] = v;
        }
    }
#pragma unroll
    for (int t = 0; t < 3; ++t)
#pragma unroll
        for (int kt = 0; kt < 3; ++kt) asm volatile("" : "+v"(Bw[t][kt]));

    const float wih2  = w_ih[s * HH + j] * ek_s;
    const float bias2 = (b_ih[s * HH + j] + b_hh[s * HH + j]) * ek_s;
    const float a_mul = (s == 2) ? (-4.0f * LOG2E) : 1.0f;
    const float a_add = (s == 2) ? (2.0f * LOG2E) : 0.0f;
    const bool  te1 = (h16 == 1), te2 = (h16 >= 2);

    const float fcb = fc_b[0];
    float c = 0.0f;   // scaled domain: c' = -2*log2e * c_true

    for (int i = tid; i < HH; i += TH) fcw_s[i] = fc_w[i];

    // Bulk fc projection for window [t0, t0+NS): h(t0+i) is in hist row i+1.
    auto flush = [&](int t0) {
        for (int i = tid; i < NS; i += TH) {
            const uint2* hr = (const uint2*)(hist + (i + 1) * ROWP);
            float a = 0.0f;
#pragma unroll
            for (int m = 0; m < 24; ++m) {
                uint2 u = hr[m];
                f16x2 p0 = __builtin_bit_cast(f16x2, u.x);
                f16x2 p1 = __builtin_bit_cast(f16x2, u.y);
                a = fmaf((float)p0.x, fcw_s[4 * m + 0], a);
                a = fmaf((float)p0.y, fcw_s[4 * m + 1], a);
                a = fmaf((float)p1.x, fcw_s[4 * m + 2], a);
                a = fmaf((float)p1.y, fcw_s[4 * m + 3], a);
            }
            out[(t0 + i) * BB + b] = a + fcb + xs[i];
        }
    };

    const _Float16* rd_p;  // h(t-1) k-slice base (8*h16); +4 rows per block
    _Float16*       wr_p;  // h(t) cell slot base

    auto step = [&](float gx, const int ofs) {   // ofs: constant element offset
        const uint4* p = (const uint4*)(rd_p + ofs);
        uint4 u0 = p[0], u1 = p[4], u2 = p[8];   // kt stride: 32 halves = 64B
        const f16x8 a0 = __builtin_bit_cast(f16x8, u0);
        const f16x8 a1 = __builtin_bit_cast(f16x8, u1);
        const f16x8 a2 = __builtin_bit_cast(f16x8, u2);

        // C-init carries gx: lane (h16,rIn) seeds elem (row 4h16, col rIn)
        // of every tile and reads back exactly its own seed from tile te.
        const f32x4 cz = {gx, 0.f, 0.f, 0.f};
        f32x4 acc[3] = {cz, cz, cz};
        // kt-outer: 3 tile-chains interleave; C-forwarding runs at full rate.
#pragma unroll
        for (int t = 0; t < 3; ++t)
            acc[t] = __builtin_amdgcn_mfma_f32_16x16x32_f16(a0, Bw[t][0], acc[t], 0, 0, 0);
#pragma unroll
        for (int t = 0; t < 3; ++t)
            acc[t] = __builtin_amdgcn_mfma_f32_16x16x32_f16(a1, Bw[t][1], acc[t], 0, 0, 0);
#pragma unroll
        for (int t = 0; t < 3; ++t)
            acc[t] = __builtin_amdgcn_mfma_f32_16x16x32_f16(a2, Bw[t][2], acc[t], 0, 0, 0);

        // Rows are replicas -> reg 0 always; 2-cndmask tile select by te.
        float pre = te1 ? acc[1][0] : acc[0][0];
        pre       = te2 ? acc[2][0] : pre;

        const float act =
            fmaf(__builtin_amdgcn_rcpf(1.0f + __builtin_amdgcn_exp2f(pre)),
                 a_mul, a_add);
        const float fv = dpp_bcast<DPP_B1>(act);
        const float gv = dpp_bcast<DPP_B2>(act);   // already -2k-scaled
        const float ov = dpp_bcast<DPP_B3>(act);
        c = fmaf(fv, c, act * gv);                 // scaled domain
        const float rt = __builtin_amdgcn_rcpf(1.0f + __builtin_amdgcn_exp2f(c));
        const float h  = fmaf(ov + ov, rt, -ov);   // o * tanh(c_true)
        if (s == 0 && h16 < 3) *(wr_p + ofs) = (_Float16)h;
        __syncthreads();
    };

    for (int w = 0; w < TT / NS; ++w) {
        const int t0 = w * NS;
        if (w == 0) {
            if (tid < 48) ((uint32_t*)hist)[tid] = 0u;  // row 0 = h(-1) = 0
        } else {
            flush(t0 - NS);                              // old xs + rows 1..512
            if (tid < 48)                                // row 512 -> row 0
                ((uint32_t*)hist)[tid] = ((const uint32_t*)(hist + NS * ROWP))[tid];
        }
        __syncthreads();
        for (int i = tid; i < NS; i += TH) xs[i] = x[(t0 + i) * BB + b];
        __syncthreads();

        rd_p = hist + 8 * h16;
        wr_p = hist + ROWP + j;
        for (int tt = 0; tt < NS; tt += 4) {
            const float4 xq = *(const float4*)(xs + tt);  // broadcast
            const float gx0 = fmaf(xq.x, wih2, bias2);    // off-chain
            const float gx1 = fmaf(xq.y, wih2, bias2);
            const float gx2 = fmaf(xq.z, wih2, bias2);
            const float gx3 = fmaf(xq.w, wih2, bias2);
            step(gx0, 0 * ROWP);
            step(gx1, 1 * ROWP);
            step(gx2, 2 * ROWP);
            step(gx3, 3 * ROWP);
            rd_p += 4 * ROWP;
            wr_p += 4 * ROWP;
        }
    }
    flush(TT - NS);   // last window (loop ended with a barrier)
}

extern "C" void kernel_launch(void* const* d_in, const int* in_sizes, int n_in,
                              void* d_out, int out_size, void* d_ws, size_t ws_size,
                              hipStream_t stream) {
    const float* x    = (const float*)d_in[0];
    const float* w_ih = (const float*)d_in[1];
    const float* w_hh = (const float*)d_in[2];
    const float* b_ih = (const float*)d_in[3];
    const float* b_hh = (const float*)d_in[4];
    const float* fc_w = (const float*)d_in[5];
    const float* fc_b = (const float*)d_in[6];
    float* out = (float*)d_out;

    lstm_kernel<<<dim3(BB), dim3(TH), 0, stream>>>(x, w_ih, w_hh, b_ih, b_hh,
                                                   fc_w, fc_b, out);
}